// Round 10
// baseline (1290.272 us; speedup 1.0000x reference)
//
#include <hip/hip_runtime.h>
#include <hip/hip_bf16.h>
#include <hip/hip_fp16.h>

#define N_D 256
#define NBLK 832   // edge-pass grid; must match between count/partition kernels

typedef __attribute__((ext_vector_type(8))) short bf16x8;
typedef __attribute__((ext_vector_type(4))) float f32x4;
typedef __attribute__((ext_vector_type(2))) float f32x2;
typedef __attribute__((ext_vector_type(2))) int   i32x2;

// f32 -> bf16 round-to-nearest-even (finite inputs)
__device__ __forceinline__ unsigned short f2bf(float f) {
  union { float f; unsigned u; } c; c.f = f;
  unsigned u = c.u;
  return (unsigned short)((u + 0x7fffu + ((u >> 16) & 1u)) >> 16);
}
__device__ __forceinline__ float asf(unsigned u) {
  union { unsigned u; float f; } c; c.u = u;
  return c.f;
}
__device__ __forceinline__ int grp_of(int r, unsigned gmagic) {
  int g = (int)(((unsigned long long)(unsigned)r * gmagic) >> 37);
  return min(g, 7);
}

// ---------- CSR build pass 1: row histogram (XCD-local replicas) ----------
__global__ __launch_bounds__(256) void count_kernel(
    const int* __restrict__ rows, int* __restrict__ cnt8, int* __restrict__ cntT,
    int n_edges, unsigned gmagic, int M) {
  __shared__ int lcnt[8];
  if (threadIdx.x < 8) lcnt[threadIdx.x] = 0;
  __syncthreads();
  int* __restrict__ cnt = cnt8 + (size_t)(blockIdx.x & 7) * M;
  for (int e = blockIdx.x * 256 + threadIdx.x; e < n_edges; e += NBLK * 256) {
    const int r = __builtin_nontemporal_load(&rows[e]);
    atomicAdd(&cnt[r], 1);
    atomicAdd(&lcnt[grp_of(r, gmagic)], 1);
  }
  __syncthreads();
  if (threadIdx.x < 8) cntT[threadIdx.x * NBLK + blockIdx.x] = lcnt[threadIdx.x];
}

// ---------- sum the 8 replicas; per-block totals for the hierarchical scan ----
__global__ __launch_bounds__(256) void sumcnt_kernel(
    const int* __restrict__ cnt8, int* __restrict__ cnts,
    int* __restrict__ bsum, int M) {
  __shared__ int wred[4];
  const int i = blockIdx.x * 256 + threadIdx.x;
  int s = 0;
  if (i < M) {
#pragma unroll
    for (int k = 0; k < 8; ++k) s += cnt8[(size_t)k * M + i];
    cnts[i] = s;
  }
  int t = s;
#pragma unroll
  for (int off = 32; off; off >>= 1) t += __shfl_down(t, off, 64);
  if ((threadIdx.x & 63) == 0) wred[threadIdx.x >> 6] = t;
  __syncthreads();
  if (threadIdx.x == 0) bsum[blockIdx.x] = wred[0] + wred[1] + wred[2] + wred[3];
}

// ---------- generic small exclusive scan (1 block); outA[n] = total ----------
__global__ __launch_bounds__(1024) void scan_kernel(
    const int* __restrict__ cnt, int* __restrict__ outA,
    int* __restrict__ outB, int n) {
  __shared__ int wsum[16];
  __shared__ int carry_sh;
  const int tid = threadIdx.x;
  const int lane = tid & 63;
  const int wid = tid >> 6;
  if (tid == 0) carry_sh = 0;
  __syncthreads();
  for (int base = 0; base < n; base += 4096) {
    const int i0 = base + tid * 4;
    int4 v = make_int4(0, 0, 0, 0);
    if (i0 + 3 < n) v = *reinterpret_cast<const int4*>(cnt + i0);
    else {
      if (i0     < n) v.x = cnt[i0];
      if (i0 + 1 < n) v.y = cnt[i0 + 1];
      if (i0 + 2 < n) v.z = cnt[i0 + 2];
    }
    const int s1 = v.x, s2 = s1 + v.y, s3 = s2 + v.z, s4 = s3 + v.w;
    int ws = s4;
#pragma unroll
    for (int off = 1; off < 64; off <<= 1) {
      int o = __shfl_up(ws, off, 64);
      if (lane >= off) ws += o;
    }
    if (lane == 63) wsum[wid] = ws;
    __syncthreads();
    if (wid == 0) {
      int t = (lane < 16) ? wsum[lane] : 0;
#pragma unroll
      for (int off = 1; off < 16; off <<= 1) {
        int o = __shfl_up(t, off, 64);
        if (lane >= off) t += o;
      }
      if (lane < 16) wsum[lane] = t;
    }
    __syncthreads();
    const int carry = carry_sh;
    const int tbase = carry + (wid ? wsum[wid - 1] : 0) + ws - s4;  // exclusive
    if (i0     < n) { outA[i0]     = tbase;      outB[i0]     = tbase; }
    if (i0 + 1 < n) { outA[i0 + 1] = tbase + s1; outB[i0 + 1] = tbase + s1; }
    if (i0 + 2 < n) { outA[i0 + 2] = tbase + s2; outB[i0 + 2] = tbase + s2; }
    if (i0 + 3 < n) { outA[i0 + 3] = tbase + s3; outB[i0 + 3] = tbase + s3; }
    __syncthreads();
    if (tid == 0) carry_sh = carry + wsum[15];
    __syncthreads();
  }
  if (tid == 0) outA[n] = carry_sh;
}

// ---------- apply block offsets: row_ptr/cursor = excl-scan(cnts) ----------
__global__ __launch_bounds__(256) void scan_apply_kernel(
    const int* __restrict__ cnts, const int* __restrict__ bofs,
    int* __restrict__ row_ptr, int* __restrict__ cursor, int M) {
  __shared__ int wsum[4];
  const int tid = threadIdx.x;
  const int lane = tid & 63;
  const int wid = tid >> 6;
  const int i = blockIdx.x * 256 + tid;
  const int v = (i < M) ? cnts[i] : 0;
  int s = v;
#pragma unroll
  for (int off = 1; off < 64; off <<= 1) {
    int o = __shfl_up(s, off, 64);
    if (lane >= off) s += o;
  }
  if (lane == 63) wsum[wid] = s;
  __syncthreads();
  int add = 0;
  for (int k = 0; k < wid; ++k) add += wsum[k];
  const int excl = bofs[blockIdx.x] + add + s - v;
  if (i < M) { row_ptr[i] = excl; cursor[i] = excl; }
  if (i == M) row_ptr[M] = bofs[gridDim.x];   // total
}

// ---------- pass 2: partition edges into 8 contiguous group segments ----------
__global__ __launch_bounds__(256) void partition_kernel(
    const int* __restrict__ rows, const int* __restrict__ cols,
    const float* __restrict__ vals, const int* __restrict__ pofsT,
    i32x2* __restrict__ part, int n_edges, unsigned gmagic) {
  __shared__ int lofs[8];
  if (threadIdx.x < 8) lofs[threadIdx.x] = pofsT[threadIdx.x * NBLK + blockIdx.x];
  __syncthreads();
  for (int e = blockIdx.x * 256 + threadIdx.x; e < n_edges; e += NBLK * 256) {
    const int r = __builtin_nontemporal_load(&rows[e]);
    const int c = __builtin_nontemporal_load(&cols[e]);
    const float vl = __builtin_nontemporal_load(&vals[e]);
    const int g = grp_of(r, gmagic);
    const int slot = atomicAdd(&lofs[g], 1);
    const unsigned short hb = __half_as_ushort(__float2half_rn(vl * 0.5f));
    i32x2 rv;
    rv.x = r;
    rv.y = (int)(((unsigned)c << 15) | ((unsigned)hb >> 1));
    __builtin_nontemporal_store(rv, &part[slot]);
  }
}

// ---------- pass 3: scatter within XCD-local group (write-merge friendly) ----------
__global__ __launch_bounds__(256) void scatter2_kernel(
    const i32x2* __restrict__ part, const int* __restrict__ pofsT,
    int* __restrict__ cursor, unsigned* __restrict__ colpack) {
  const int g  = blockIdx.x & 7;
  const int bk = blockIdx.x >> 3;
  const int nb = gridDim.x >> 3;
  const int s0 = pofsT[g * NBLK];
  const int s1 = pofsT[(g + 1) * NBLK];   // g=7 -> pofsT[8*NBLK] = total
  for (int i = s0 + bk * 256 + threadIdx.x; i < s1; i += nb * 256) {
    const i32x2 rv = __builtin_nontemporal_load(&part[i]);
    const int pos = atomicAdd(&cursor[rv.x], 1);
    colpack[pos] = (unsigned)rv.y;   // keep cached: lines merge in XCD-local L2
  }
}

// ---------- SpMM, feature-sliced, round-6 decode, 16-deep MLP ----------
// 4 slices x 64 features (128B). slice = blockIdx&3 -> XCDs {s, s+4}.
// One shfl of the raw packed word per edge; decode per-lane (VALU) after.
template <bool RELU, bool F32OUT>
__global__ __launch_bounds__(256) void spmm_slice(
    const unsigned short* __restrict__ hin, const int* __restrict__ row_ptr,
    const unsigned* __restrict__ colpack, void* __restrict__ hout,
    int n_nodes) {
  const int slice = blockIdx.x & 3;
  const int lane = threadIdx.x & 63;
  const int half = lane >> 5;
  const int sub  = lane & 31;
  const int wgid = ((blockIdx.x >> 2) * 256 + threadIdx.x) >> 6;  // node-pair id
  const int node = wgid * 2 + half;
  const bool ok = node < n_nodes;
  int start = 0, end = 0;
  if (ok) { start = row_ptr[node]; end = row_ptr[node + 1]; }

  const unsigned* __restrict__ hinw = reinterpret_cast<const unsigned*>(hin);
  const int fofs = slice * 32 + sub;       // uint index within a 128-uint row
  const int sbase = half << 5;

  float acc0 = 0.f, acc1 = 0.f;

  for (int base = start; base < end; base += 32) {
    const int cnt = min(32, end - base);
    unsigned u = 0;                        // u=0 -> (col=0, val=0) dummy
    if (base + sub < end) u = __builtin_nontemporal_load(&colpack[base + sub]);
    for (int t = 0; t < cnt; t += 16) {
      unsigned hv[16];
      float v[16];
#pragma unroll
      for (int j = 0; j < 16; ++j) {
        const unsigned ue = (unsigned)__shfl((int)u, sbase + t + j, 64);
        const int c = (int)(ue >> 15);
        v[j] = __half2float(__ushort_as_half((unsigned short)((ue & 0x7fffu) << 1)));
        hv[j] = hinw[(size_t)c * 128 + fofs];   // 16 independent 4B gathers
      }
#pragma unroll
      for (int j = 0; j < 16; ++j) {
        acc0 += v[j] * asf(hv[j] << 16);
        acc1 += v[j] * asf(hv[j] & 0xffff0000u);
      }
    }
  }
  if (ok) {
    if (RELU) { acc0 = fmaxf(acc0, 0.f); acc1 = fmaxf(acc1, 0.f); }
    if (F32OUT) {
      f32x2 o; o.x = acc0; o.y = acc1;
      __builtin_nontemporal_store(o, reinterpret_cast<f32x2*>(hout) + (size_t)node * 128 + fofs);
    } else {
      unsigned o = (unsigned)f2bf(acc0) | ((unsigned)f2bf(acc1) << 16);
      __builtin_nontemporal_store(o, reinterpret_cast<unsigned*>(hout) + (size_t)node * 128 + fofs);
    }
  }
}

// ---------- W[k][n] fp32 -> WT[n][k] bf16, both weights in one dispatch ----------
__global__ __launch_bounds__(256) void wconv_kernel(
    const float* __restrict__ W0, const float* __restrict__ W1,
    unsigned short* __restrict__ WT0, unsigned short* __restrict__ WT1) {
  const int w = blockIdx.x >> 8;
  const int k = blockIdx.x & 255;
  const int n = threadIdx.x;
  const float* W = w ? W1 : W0;
  unsigned short* WT = w ? WT1 : WT0;
  WT[(size_t)n * N_D + k] = f2bf(W[(size_t)k * N_D + n]);
}

// ---------- GEMM: H[M,256] @ W via WT(bf16), A read once per block ----------
// Block 256 thr = 4 waves; wave w: rows [bx*64 + w*16, +16) x cols [0,256).
// AF32: A is fp32 (raw x input), converted to bf16 in the fragment load.
template <bool AF32>
__global__ __launch_bounds__(256) void gemm2(
    const void* __restrict__ H, const unsigned short* __restrict__ WT,
    unsigned short* __restrict__ C, int M) {
  const int wave = threadIdx.x >> 6;
  const int lane = threadIdx.x & 63;
  const int m = lane & 15;
  const int p = lane >> 4;
  const int row0 = blockIdx.x * 64 + wave * 16;

  f32x4 acc[16];
#pragma unroll
  for (int i = 0; i < 16; ++i) acc[i] = (f32x4){0.f, 0.f, 0.f, 0.f};

  const int r = row0 + m;
  const bool rok = r < M;

  for (int k0 = 0; k0 < N_D; k0 += 32) {
    bf16x8 a = {0, 0, 0, 0, 0, 0, 0, 0};
    if (rok) {
      if (AF32) {
        const float* ap = (const float*)H + (size_t)r * N_D + k0 + p * 8;
        const float4 f0 = *reinterpret_cast<const float4*>(ap);
        const float4 f1 = *reinterpret_cast<const float4*>(ap + 4);
        a[0] = f2bf(f0.x); a[1] = f2bf(f0.y); a[2] = f2bf(f0.z); a[3] = f2bf(f0.w);
        a[4] = f2bf(f1.x); a[5] = f2bf(f1.y); a[6] = f2bf(f1.z); a[7] = f2bf(f1.w);
      } else {
        a = *reinterpret_cast<const bf16x8*>(
            (const unsigned short*)H + (size_t)r * N_D + k0 + p * 8);
      }
    }
#pragma unroll
    for (int nt = 0; nt < 16; ++nt) {
      const bf16x8 b = *reinterpret_cast<const bf16x8*>(
          WT + (size_t)(nt * 16 + m) * N_D + k0 + p * 8);
      acc[nt] = __builtin_amdgcn_mfma_f32_16x16x32_bf16(a, b, acc[nt], 0, 0, 0);
    }
  }

  // C/D layout: col = lane&15 (=m), row = p*4 + rr within the 16x16 tile
#pragma unroll
  for (int nt = 0; nt < 16; ++nt) {
    const int col = nt * 16 + m;
#pragma unroll
    for (int rr = 0; rr < 4; ++rr) {
      const int r2 = row0 + p * 4 + rr;
      if (r2 < M) {
        C[(size_t)r2 * N_D + col] = f2bf(acc[nt][rr]);
      }
    }
  }
}

extern "C" void kernel_launch(void* const* d_in, const int* in_sizes, int n_in,
                              void* d_out, int out_size, void* d_ws, size_t ws_size,
                              hipStream_t stream) {
  const float* x    = (const float*)d_in[0];
  const float* vals = (const float*)d_in[1];
  const float* W0   = (const float*)d_in[2];
  const float* W1   = (const float*)d_in[3];
  const int*   rows = (const int*)d_in[4];
  const int*   cols = (const int*)d_in[5];

  const int n_edges = in_sizes[1];
  const int M = in_sizes[0] / N_D;        // 100000
  const size_t n_feat = (size_t)M * N_D;  // 25.6M elements

  char* ws = (char*)d_ws;
  unsigned short* hA      = (unsigned short*)(ws);                  // 51.2 MB bf16
  unsigned*       colpack = (unsigned*)(ws + 51200000);             // 12.8 MB
  int*            row_ptr = (int*)(ws + 64000000);                  // 400 KB
  int*            cursor  = (int*)(ws + 64400128);                  // 400 KB
  int*            cnt8    = (int*)(ws + 64800256);                  // 3.2 MB
  int*            cnts    = (int*)(ws + 68000384);                  // 400 KB
  int*            bsum    = (int*)(ws + 68400512);                  // 2 KB
  int*            bofs    = (int*)(ws + 68402560);                  // 2 KB
  int*            bscr    = (int*)(ws + 68404608);                  // 2 KB
  int*            cntT    = (int*)(ws + 68406656);                  // 26.9 KB
  int*            pofsT   = (int*)(ws + 68433536);                  // 26.9 KB
  int*            pscr    = (int*)(ws + 68460416);                  // 26.9 KB
  unsigned short* wt0     = (unsigned short*)(ws + 68487296);       // 128 KB
  unsigned short* wt1     = (unsigned short*)(ws + 68618368);       // 128 KB
  // d_out (102.4 MB fp32) hosts bf16/scratch buffers until the final spmm:
  unsigned short* hB   = (unsigned short*)d_out;                    // [0, 51.2 MB)
  unsigned short* hC   = (unsigned short*)d_out + n_feat;           // [51.2, 102.4 MB)
  i32x2*          part = (i32x2*)((char*)d_out + 51200000);         // build-time only

  const int Mb = (M + 255) / 256;           // 391
  const int sblocks = 4 * ((M + 7) / 8);    // 4 slices x (8 nodes per block)
  const int gblocks = (M + 63) / 64;
  const int rpg = (M + 7) / 8;              // rows per XCD group
  const unsigned gmagic = (unsigned)(((1ULL << 37) + rpg - 1) / (unsigned long long)rpg);

  // --- CSR build (once; reused by all 4 SpMMs). part lives in d_out[51.2,76.8MB) ---
  hipMemsetAsync(cnt8, 0, (size_t)8 * M * sizeof(int), stream);
  count_kernel<<<NBLK, 256, 0, stream>>>(rows, cnt8, cntT, n_edges, gmagic, M);
  sumcnt_kernel<<<Mb, 256, 0, stream>>>(cnt8, cnts, bsum, M);
  scan_kernel<<<1, 1024, 0, stream>>>(bsum, bofs, bscr, Mb);
  scan_apply_kernel<<<Mb, 256, 0, stream>>>(cnts, bofs, row_ptr, cursor, M);
  scan_kernel<<<1, 1024, 0, stream>>>(cntT, pofsT, pscr, 8 * NBLK);
  partition_kernel<<<NBLK, 256, 0, stream>>>(rows, cols, vals, pofsT, part,
                                             n_edges, gmagic);
  scatter2_kernel<<<NBLK, 256, 0, stream>>>(part, pofsT, cursor, colpack);
  wconv_kernel<<<512, 256, 0, stream>>>(W0, W1, wt0, wt1);

  // --- layer 0:  relu((0.5A)^2 (x @ W0))  [GEMM-first by associativity] ---
  gemm2<true ><<<gblocks, 256, 0, stream>>>(x,  wt0, hB, M);               // hB = x@W0 (bf16)
  spmm_slice<false, false><<<sblocks, 256, 0, stream>>>(hB, row_ptr, colpack, hA, M);
  spmm_slice<true,  false><<<sblocks, 256, 0, stream>>>(hA, row_ptr, colpack, hB, M);  // + relu

  // --- layer 1:  (0.5A)^2 (h @ W1) ---
  gemm2<false><<<gblocks, 256, 0, stream>>>(hB, wt1, hC, M);               // hC = h@W1 (bf16)
  spmm_slice<false, false><<<sblocks, 256, 0, stream>>>(hC, row_ptr, colpack, hA, M);
  spmm_slice<false, true ><<<sblocks, 256, 0, stream>>>(hA, row_ptr, colpack, d_out, M);  // fp32 out
}

// Round 11
// 1235.296 us; speedup vs baseline: 1.0445x; 1.0445x over previous
//
#include <hip/hip_runtime.h>
#include <hip/hip_bf16.h>
#include <hip/hip_fp16.h>

#define N_D 256
#define NBLK 832   // edge-pass grid; shared by count/partition/scatter2

typedef __attribute__((ext_vector_type(8))) short bf16x8;
typedef __attribute__((ext_vector_type(4))) float f32x4;

// f32 -> bf16 round-to-nearest-even (finite inputs)
__device__ __forceinline__ unsigned short f2bf(float f) {
  union { float f; unsigned u; } c; c.f = f;
  unsigned u = c.u;
  return (unsigned short)((u + 0x7fffu + ((u >> 16) & 1u)) >> 16);
}
__device__ __forceinline__ float asf(unsigned u) {
  union { unsigned u; float f; } c; c.u = u;
  return c.f;
}
__device__ __forceinline__ int grp_of(int r, unsigned gmagic) {
  int g = (int)(((unsigned long long)(unsigned)r * gmagic) >> 37);
  return min(g, 7);
}

// ---------- fat 1: row histogram (blocks < NBLK) + weight transpose ----------
// cnt8[bid%8][r]: blocks with equal bid%8 land on the same XCD (round-robin),
// so histogram atomics stay in one XCD's L2.
__global__ __launch_bounds__(256) void build1_kernel(
    const int* __restrict__ rows, int* __restrict__ cnt8, int* __restrict__ cntT,
    int n_edges, unsigned gmagic, int M,
    const float* __restrict__ W0, const float* __restrict__ W1,
    unsigned short* __restrict__ WT0, unsigned short* __restrict__ WT1) {
  if (blockIdx.x >= NBLK) {       // 512 trailing blocks: WT[n][k] = bf16(W[k][n])
    const int b = blockIdx.x - NBLK;
    const int w = b >> 8;
    const int k = b & 255;
    const int n = threadIdx.x;
    const float* W = w ? W1 : W0;
    unsigned short* WT = w ? WT1 : WT0;
    WT[(size_t)n * N_D + k] = f2bf(W[(size_t)k * N_D + n]);
    return;
  }
  __shared__ int lcnt[8];
  if (threadIdx.x < 8) lcnt[threadIdx.x] = 0;
  __syncthreads();
  int* __restrict__ cnt = cnt8 + (size_t)(blockIdx.x & 7) * M;
  for (int e = blockIdx.x * 256 + threadIdx.x; e < n_edges; e += NBLK * 256) {
    const int r = rows[e];
    atomicAdd(&cnt[r], 1);
    atomicAdd(&lcnt[grp_of(r, gmagic)], 1);
  }
  __syncthreads();
  if (threadIdx.x < 8) cntT[threadIdx.x * NBLK + blockIdx.x] = lcnt[threadIdx.x];
}

// ---------- sum the 8 replicas; per-block totals for the hierarchical scan ----
__global__ __launch_bounds__(256) void sumcnt_kernel(
    const int* __restrict__ cnt8, int* __restrict__ cnts,
    int* __restrict__ bsum, int M) {
  __shared__ int wred[4];
  const int i = blockIdx.x * 256 + threadIdx.x;
  int s = 0;
  if (i < M) {
#pragma unroll
    for (int k = 0; k < 8; ++k) s += cnt8[(size_t)k * M + i];
    cnts[i] = s;
  }
  int t = s;
#pragma unroll
  for (int off = 32; off; off >>= 1) t += __shfl_down(t, off, 64);
  if ((threadIdx.x & 63) == 0) wred[threadIdx.x >> 6] = t;
  __syncthreads();
  if (threadIdx.x == 0) bsum[blockIdx.x] = wred[0] + wred[1] + wred[2] + wred[3];
}

// ---------- 256-thread exclusive scan (device fn); out[n] = total ----------
__device__ void scan256(const int* __restrict__ in, int* __restrict__ out, int n) {
  __shared__ int wsum[4];
  __shared__ int carry_sh;
  const int tid = threadIdx.x;
  const int lane = tid & 63;
  const int wid = tid >> 6;
  if (tid == 0) carry_sh = 0;
  __syncthreads();
  for (int base = 0; base < n; base += 1024) {
    const int i0 = base + tid * 4;
    int4 v = make_int4(0, 0, 0, 0);
    if (i0 + 3 < n) v = *reinterpret_cast<const int4*>(in + i0);
    else {
      if (i0     < n) v.x = in[i0];
      if (i0 + 1 < n) v.y = in[i0 + 1];
      if (i0 + 2 < n) v.z = in[i0 + 2];
    }
    const int s1 = v.x, s2 = s1 + v.y, s3 = s2 + v.z, s4 = s3 + v.w;
    int ws = s4;
#pragma unroll
    for (int off = 1; off < 64; off <<= 1) {
      int o = __shfl_up(ws, off, 64);
      if (lane >= off) ws += o;
    }
    if (lane == 63) wsum[wid] = ws;
    __syncthreads();
    if (wid == 0) {
      int t = (lane < 4) ? wsum[lane] : 0;
#pragma unroll
      for (int off = 1; off < 4; off <<= 1) {
        int o = __shfl_up(t, off, 64);
        if (lane >= off) t += o;
      }
      if (lane < 4) wsum[lane] = t;
    }
    __syncthreads();
    const int carry = carry_sh;
    const int tbase = carry + (wid ? wsum[wid - 1] : 0) + ws - s4;  // exclusive
    if (i0     < n) out[i0]     = tbase;
    if (i0 + 1 < n) out[i0 + 1] = tbase + s1;
    if (i0 + 2 < n) out[i0 + 2] = tbase + s2;
    if (i0 + 3 < n) out[i0 + 3] = tbase + s3;
    __syncthreads();                 // everyone done with carry_sh/wsum
    if (tid == 0) carry_sh = carry + wsum[3];
    __syncthreads();
  }
  if (tid == 0) out[n] = carry_sh;
}

// ---------- both small scans in one launch (block 0: bsum, block 1: cntT) ----
__global__ __launch_bounds__(256) void scan2_kernel(
    const int* __restrict__ bsum, int* __restrict__ bofs, int Mb,
    const int* __restrict__ cntT, int* __restrict__ pofsT) {
  if (blockIdx.x == 0) scan256(bsum, bofs, Mb);
  else                 scan256(cntT, pofsT, 8 * NBLK);
}

// ---------- fat 2: scan_apply (blocks < Mb) + partition (blocks >= Mb) -------
__global__ __launch_bounds__(256) void build2_kernel(
    const int* __restrict__ cnts, const int* __restrict__ bofs,
    int* __restrict__ row_ptr, int* __restrict__ cursor, int M, int Mb,
    const int* __restrict__ rows, const int* __restrict__ cols,
    const float* __restrict__ vals, const int* __restrict__ pofsT,
    int2* __restrict__ part, int n_edges, unsigned gmagic) {
  __shared__ int shmem[8];
  if (blockIdx.x < Mb) {
    // scan_apply: row_ptr/cursor = bofs[block] + intra-block exclusive scan
    const int tid = threadIdx.x;
    const int lane = tid & 63;
    const int wid = tid >> 6;
    const int i = blockIdx.x * 256 + tid;
    const int v = (i < M) ? cnts[i] : 0;
    int s = v;
#pragma unroll
    for (int off = 1; off < 64; off <<= 1) {
      int o = __shfl_up(s, off, 64);
      if (lane >= off) s += o;
    }
    if (lane == 63) shmem[wid] = s;
    __syncthreads();
    int add = 0;
    for (int k = 0; k < wid; ++k) add += shmem[k];
    const int excl = bofs[blockIdx.x] + add + s - v;
    if (i < M) { row_ptr[i] = excl; cursor[i] = excl; }
    if (i == M) row_ptr[M] = bofs[Mb];   // total edges
  } else {
    // partition: edges -> 8 contiguous XCD-group segments of `part`
    const int pb = blockIdx.x - Mb;      // 0..NBLK-1
    if (threadIdx.x < 8) shmem[threadIdx.x] = pofsT[threadIdx.x * NBLK + pb];
    __syncthreads();
    for (int e = pb * 256 + threadIdx.x; e < n_edges; e += NBLK * 256) {
      const int r = rows[e];
      const int g = grp_of(r, gmagic);
      const int slot = atomicAdd(&shmem[g], 1);
      const unsigned short hb = __half_as_ushort(__float2half_rn(vals[e] * 0.5f));
      int2 rv;
      rv.x = r;
      rv.y = (int)(((unsigned)cols[e] << 15) | ((unsigned)hb >> 1));
      part[slot] = rv;
    }
  }
}

// ---------- scatter within XCD-local group (write-merge friendly) ------------
__global__ __launch_bounds__(256) void scatter2_kernel(
    const int2* __restrict__ part, const int* __restrict__ pofsT,
    int* __restrict__ cursor, unsigned* __restrict__ colpack) {
  const int g  = blockIdx.x & 7;
  const int bk = blockIdx.x >> 3;
  const int nb = gridDim.x >> 3;
  const int s0 = pofsT[g * NBLK];
  const int s1 = pofsT[(g + 1) * NBLK];   // g=7 -> pofsT[8*NBLK] = total
  for (int i = s0 + bk * 256 + threadIdx.x; i < s1; i += nb * 256) {
    const int2 rv = part[i];
    const int pos = atomicAdd(&cursor[rv.x], 1);
    colpack[pos] = (unsigned)rv.y;
  }
}

// ---------- SpMM, feature-sliced (round-6 config: MLP 8, inline decode) ------
// 4 slices x 64 features (128B). slice = blockIdx&3 -> XCDs {s, s+4}: per-XCD
// gather working set 12.8 MB. Half-wave = one node (32 lanes x 4B = 128B).
template <bool RELU, bool F32OUT>
__global__ __launch_bounds__(256) void spmm_slice(
    const unsigned short* __restrict__ hin, const int* __restrict__ row_ptr,
    const unsigned* __restrict__ colpack, void* __restrict__ hout,
    int n_nodes) {
  const int slice = blockIdx.x & 3;
  const int lane = threadIdx.x & 63;
  const int half = lane >> 5;
  const int sub  = lane & 31;
  const int wgid = ((blockIdx.x >> 2) * 256 + threadIdx.x) >> 6;  // node-pair id
  const int node = wgid * 2 + half;
  const bool ok = node < n_nodes;
  int start = 0, end = 0;
  if (ok) { start = row_ptr[node]; end = row_ptr[node + 1]; }

  const unsigned* __restrict__ hinw = reinterpret_cast<const unsigned*>(hin);
  const int fofs = slice * 32 + sub;       // uint index within a 128-uint row
  const int sbase = half << 5;

  float acc0 = 0.f, acc1 = 0.f;

  for (int base = start; base < end; base += 32) {
    const int cnt = min(32, end - base);
    unsigned u = 0;                        // u=0 -> (col=0, val=0) dummy
    if (base + sub < end) u = __builtin_nontemporal_load(&colpack[base + sub]);
    for (int t = 0; t < cnt; t += 8) {
      unsigned hv[8];
      float v[8];
#pragma unroll
      for (int j = 0; j < 8; ++j) {
        const unsigned ue = (unsigned)__shfl((int)u, sbase + t + j, 64);
        const int c = (int)(ue >> 15);
        // (ue<<1) low 16 bits == packed f16 with LSB zeroed — same as before
        v[j] = __half2float(__ushort_as_half((unsigned short)(ue << 1)));
        hv[j] = hinw[(size_t)c * 128 + fofs];   // 8 independent 4B gathers
      }
#pragma unroll
      for (int j = 0; j < 8; ++j) {
        acc0 += v[j] * asf(hv[j] << 16);
        acc1 += v[j] * asf(hv[j] & 0xffff0000u);
      }
    }
  }
  if (ok) {
    if (RELU) { acc0 = fmaxf(acc0, 0.f); acc1 = fmaxf(acc1, 0.f); }
    if (F32OUT) {
      reinterpret_cast<float2*>(hout)[(size_t)node * 128 + fofs] =
          make_float2(acc0, acc1);
    } else {
      reinterpret_cast<unsigned*>(hout)[(size_t)node * 128 + fofs] =
          (unsigned)f2bf(acc0) | ((unsigned)f2bf(acc1) << 16);
    }
  }
}

// ---------- GEMM: 128 rows/block, 2 row-frags/wave x 16 col-frags ------------
// Wave w: rows [bx*128 + w*32, +32) x cols [0,256). B loaded once per 2 MFMA.
template <bool AF32>
__global__ __launch_bounds__(256) void gemm3(
    const void* __restrict__ H, const unsigned short* __restrict__ WT,
    unsigned short* __restrict__ C, int M) {
  const int wave = threadIdx.x >> 6;
  const int lane = threadIdx.x & 63;
  const int m = lane & 15;
  const int p = lane >> 4;
  const int row0 = blockIdx.x * 128 + wave * 32;

  f32x4 acc0[16], acc1[16];
#pragma unroll
  for (int i = 0; i < 16; ++i) {
    acc0[i] = (f32x4){0.f, 0.f, 0.f, 0.f};
    acc1[i] = (f32x4){0.f, 0.f, 0.f, 0.f};
  }

  const int r0 = row0 + m;
  const int r1 = row0 + 16 + m;
  const bool ok0 = r0 < M, ok1 = r1 < M;

  for (int k0 = 0; k0 < N_D; k0 += 32) {
    bf16x8 a0 = {0,0,0,0,0,0,0,0}, a1 = {0,0,0,0,0,0,0,0};
    if (AF32) {
      if (ok0) {
        const float* ap = (const float*)H + (size_t)r0 * N_D + k0 + p * 8;
        const float4 f0 = *reinterpret_cast<const float4*>(ap);
        const float4 f1 = *reinterpret_cast<const float4*>(ap + 4);
        a0[0]=f2bf(f0.x); a0[1]=f2bf(f0.y); a0[2]=f2bf(f0.z); a0[3]=f2bf(f0.w);
        a0[4]=f2bf(f1.x); a0[5]=f2bf(f1.y); a0[6]=f2bf(f1.z); a0[7]=f2bf(f1.w);
      }
      if (ok1) {
        const float* ap = (const float*)H + (size_t)r1 * N_D + k0 + p * 8;
        const float4 f0 = *reinterpret_cast<const float4*>(ap);
        const float4 f1 = *reinterpret_cast<const float4*>(ap + 4);
        a1[0]=f2bf(f0.x); a1[1]=f2bf(f0.y); a1[2]=f2bf(f0.z); a1[3]=f2bf(f0.w);
        a1[4]=f2bf(f1.x); a1[5]=f2bf(f1.y); a1[6]=f2bf(f1.z); a1[7]=f2bf(f1.w);
      }
    } else {
      if (ok0) a0 = *reinterpret_cast<const bf16x8*>(
          (const unsigned short*)H + (size_t)r0 * N_D + k0 + p * 8);
      if (ok1) a1 = *reinterpret_cast<const bf16x8*>(
          (const unsigned short*)H + (size_t)r1 * N_D + k0 + p * 8);
    }
#pragma unroll
    for (int nt = 0; nt < 16; ++nt) {
      const bf16x8 b = *reinterpret_cast<const bf16x8*>(
          WT + (size_t)(nt * 16 + m) * N_D + k0 + p * 8);
      acc0[nt] = __builtin_amdgcn_mfma_f32_16x16x32_bf16(a0, b, acc0[nt], 0, 0, 0);
      acc1[nt] = __builtin_amdgcn_mfma_f32_16x16x32_bf16(a1, b, acc1[nt], 0, 0, 0);
    }
  }

  // C/D layout: col = lane&15 (=m), row = p*4 + rr within each 16x16 tile
#pragma unroll
  for (int nt = 0; nt < 16; ++nt) {
    const int col = nt * 16 + m;
#pragma unroll
    for (int rr = 0; rr < 4; ++rr) {
      const int ra = row0 + p * 4 + rr;
      const int rb = ra + 16;
      if (ra < M) C[(size_t)ra * N_D + col] = f2bf(acc0[nt][rr]);
      if (rb < M) C[(size_t)rb * N_D + col] = f2bf(acc1[nt][rr]);
    }
  }
}

extern "C" void kernel_launch(void* const* d_in, const int* in_sizes, int n_in,
                              void* d_out, int out_size, void* d_ws, size_t ws_size,
                              hipStream_t stream) {
  const float* x    = (const float*)d_in[0];
  const float* vals = (const float*)d_in[1];
  const float* W0   = (const float*)d_in[2];
  const float* W1   = (const float*)d_in[3];
  const int*   rows = (const int*)d_in[4];
  const int*   cols = (const int*)d_in[5];

  const int n_edges = in_sizes[1];
  const int M = in_sizes[0] / N_D;        // 100000
  const size_t n_feat = (size_t)M * N_D;  // 25.6M elements

  char* ws = (char*)d_ws;
  unsigned short* hA      = (unsigned short*)(ws);                  // 51.2 MB bf16
  unsigned*       colpack = (unsigned*)(ws + 51200000);             // 12.8 MB
  int*            row_ptr = (int*)(ws + 64000000);                  // 400 KB
  int*            cursor  = (int*)(ws + 64400128);                  // 400 KB
  int*            cnt8    = (int*)(ws + 64800256);                  // 3.2 MB
  int*            cnts    = (int*)(ws + 68000384);                  // 400 KB
  int*            bsum    = (int*)(ws + 68400512);                  // 2 KB
  int*            bofs    = (int*)(ws + 68402560);                  // 2 KB
  int*            cntT    = (int*)(ws + 68406656);                  // 26.7 KB
  int*            pofsT   = (int*)(ws + 68433536);                  // 26.7 KB
  unsigned short* wt0     = (unsigned short*)(ws + 68487296);       // 128 KB
  unsigned short* wt1     = (unsigned short*)(ws + 68618368);       // 128 KB
  // d_out (102.4 MB fp32) hosts bf16/scratch buffers until the final spmm:
  unsigned short* hB   = (unsigned short*)d_out;                    // [0, 51.2 MB)
  unsigned short* hC   = (unsigned short*)d_out + n_feat;           // [51.2, 102.4 MB)
  int2*           part = (int2*)((char*)d_out + 51200000);          // build-time only

  const int Mb = (M + 255) / 256;           // 391
  const int sblocks = 4 * ((M + 7) / 8);    // 4 slices x (8 nodes per block)
  const int gblocks = (M + 127) / 128;      // 782
  const int rpg = (M + 7) / 8;              // rows per XCD group
  const unsigned gmagic = (unsigned)(((1ULL << 37) + rpg - 1) / (unsigned long long)rpg);

  // --- CSR build (once; reused by all 4 SpMMs). part lives in d_out[51.2,76.8MB) ---
  hipMemsetAsync(cnt8, 0, (size_t)8 * M * sizeof(int), stream);
  build1_kernel<<<NBLK + 512, 256, 0, stream>>>(rows, cnt8, cntT, n_edges, gmagic, M,
                                                W0, W1, wt0, wt1);
  sumcnt_kernel<<<Mb, 256, 0, stream>>>(cnt8, cnts, bsum, M);
  scan2_kernel<<<2, 256, 0, stream>>>(bsum, bofs, Mb, cntT, pofsT);
  build2_kernel<<<Mb + NBLK, 256, 0, stream>>>(cnts, bofs, row_ptr, cursor, M, Mb,
                                               rows, cols, vals, pofsT, part,
                                               n_edges, gmagic);
  scatter2_kernel<<<NBLK, 256, 0, stream>>>(part, pofsT, cursor, colpack);

  // --- layer 0:  relu((0.5A)^2 (x @ W0))  [GEMM-first by associativity] ---
  gemm3<true ><<<gblocks, 256, 0, stream>>>(x,  wt0, hB, M);               // hB = x@W0
  spmm_slice<false, false><<<sblocks, 256, 0, stream>>>(hB, row_ptr, colpack, hA, M);
  spmm_slice<true,  false><<<sblocks, 256, 0, stream>>>(hA, row_ptr, colpack, hB, M);

  // --- layer 1:  (0.5A)^2 (h @ W1) ---
  gemm3<false><<<gblocks, 256, 0, stream>>>(hB, wt1, hC, M);               // hC = h@W1
  spmm_slice<false, false><<<sblocks, 256, 0, stream>>>(hC, row_ptr, colpack, hA, M);
  spmm_slice<false, true ><<<sblocks, 256, 0, stream>>>(hA, row_ptr, colpack, d_out, M);
}